// Round 2
// baseline (2363.555 us; speedup 1.0000x reference)
//
#include <hip/hip_runtime.h>

#define NNODES 100000
#define NEDGES 1600000
#define FIN 128
#define FHID 128
#define FOUT 64

// CSR-build pipeline geometry: no global atomics anywhere.
#define RNG 6          // node ranges
#define RS 16672       // range size (ints); RNG*RS = 100032 >= N; 65 KB LDS
#define NPAD (RNG * RS)
#define NSL 16         // edge slices
#define SLICE ((NEDGES + NSL - 1) / NSL)   // 100000 edges per slice

// ---------------- stage 1: per-(slice,range) histograms via LDS ----------------
// grid = (NSL, RNG, 2); z=0 -> src array, z=1 -> dst array.
// part layout: part[a][s][node] at ((a*NSL + s)*NPAD + node). Plain stores only.
__global__ __launch_bounds__(256) void hist_part_kernel(const int* __restrict__ src,
                                                        const int* __restrict__ dst,
                                                        int* __restrict__ part, int E) {
  __shared__ int h[RS];
  const int s = blockIdx.x, r = blockIdx.y, a = blockIdx.z;
  const int lo = r * RS;
  const int* __restrict__ arr = a ? dst : src;
  for (int i = threadIdx.x; i < RS; i += 256) h[i] = 0;
  __syncthreads();
  const int e0 = s * SLICE, e1 = min(e0 + SLICE, E);
  for (int e = e0 + threadIdx.x; e < e1; e += 256) {
    unsigned v = (unsigned)(arr[e] - lo);
    if (v < RS) atomicAdd(&h[v], 1);   // LDS atomic
  }
  __syncthreads();
  int* __restrict__ out = part + ((size_t)a * NSL + s) * NPAD + lo;
  for (int i = threadIdx.x; i < RS; i += 256) out[i] = h[i];
}

// ---------------- stage 2: reduce over slices + fused norms ----------------
__global__ __launch_bounds__(256) void reduce_norm_kernel(const int* __restrict__ part,
                                                          int* __restrict__ deg_dst,
                                                          float* __restrict__ norm_src,
                                                          float* __restrict__ norm_dst, int n) {
  int i = blockIdx.x * 256 + threadIdx.x;
  if (i >= n) return;
  int ds = 0, dd = 0;
#pragma unroll
  for (int s = 0; s < NSL; s++) {
    ds += part[(size_t)s * NPAD + i];
    dd += part[((size_t)NSL + s) * NPAD + i];
  }
  deg_dst[i] = dd;
  norm_src[i] = rsqrtf(fmaxf((float)ds, 1.0f));
  norm_dst[i] = rsqrtf(fmaxf((float)dd, 1.0f));
}

// ---------------- exclusive scan of deg_dst -> offs (3 kernels) ----------------
__global__ __launch_bounds__(256) void scan_block_kernel(const int* __restrict__ deg,
                                                         int* __restrict__ offs,
                                                         int* __restrict__ bsums, int n) {
  __shared__ int sh[256];
  int i = blockIdx.x * 256 + threadIdx.x;
  int v = (i < n) ? deg[i] : 0;
  sh[threadIdx.x] = v;
  __syncthreads();
  for (int d = 1; d < 256; d <<= 1) {
    int t = (threadIdx.x >= d) ? sh[threadIdx.x - d] : 0;
    __syncthreads();
    sh[threadIdx.x] += t;
    __syncthreads();
  }
  if (i < n) offs[i] = sh[threadIdx.x] - v;  // exclusive
  if (threadIdx.x == 255) bsums[blockIdx.x] = sh[255];
}

__global__ void scan_sums_kernel(int* bsums, int nb) {
  if (threadIdx.x == 0 && blockIdx.x == 0) {
    int run = 0;
    for (int b = 0; b < nb; b++) { int t = bsums[b]; bsums[b] = run; run += t; }
  }
}

__global__ __launch_bounds__(256) void scan_add_kernel(int* __restrict__ offs,
                                                       const int* __restrict__ bsums, int n) {
  int i = blockIdx.x * 256 + threadIdx.x;
  if (i < n) offs[i] += bsums[blockIdx.x];
}

// ---------------- stage 3: column scan of dst-counts -> per-slice bases (in place) ----
__global__ __launch_bounds__(256) void colscan_kernel(int* __restrict__ part1,
                                                      const int* __restrict__ offs, int n) {
  int i = blockIdx.x * 256 + threadIdx.x;
  if (i >= n) return;
  int run = offs[i];
#pragma unroll
  for (int s = 0; s < NSL; s++) {
    size_t idx = (size_t)s * NPAD + i;
    int t = part1[idx];
    part1[idx] = run;
    run += t;
  }
}

// ---------------- stage 4: placement; block (slice,range) owns its positions ----------
__global__ __launch_bounds__(256) void place_kernel(const int* __restrict__ src,
                                                    const int* __restrict__ dst,
                                                    const int* __restrict__ part1,
                                                    int* __restrict__ csr, int E) {
  __shared__ int cur[RS];
  const int s = blockIdx.x, r = blockIdx.y;
  const int lo = r * RS;
  const int* __restrict__ base = part1 + (size_t)s * NPAD + lo;
  for (int i = threadIdx.x; i < RS; i += 256) cur[i] = base[i];
  __syncthreads();
  const int e0 = s * SLICE, e1 = min(e0 + SLICE, E);
  for (int e = e0 + threadIdx.x; e < e1; e += 256) {
    int d = dst[e];
    unsigned v = (unsigned)(d - lo);
    if (v < RS) {
      int p = atomicAdd(&cur[v], 1);   // LDS atomic; positions exclusive to this block
      csr[p] = src[e];
    }
  }
}

// ---------------- GEMM: Y[n,c] = norm[n] * sum_k X[n,k] * W[k,c] ----------------

template <int CTOT>
__global__ __launch_bounds__(256) void gemm_scale(const float* __restrict__ X,
                                                  const float* __restrict__ W,
                                                  const float* __restrict__ norm,
                                                  float* __restrict__ Y, int nrows) {
  constexpr int K = 128;
  constexpr int ROWS = 64;
  constexpr int CTILE = 64;
  __shared__ float Xs[ROWS][K];    // 32 KB
  __shared__ float Ws[K][CTILE];   // 32 KB
  const int tid = threadIdx.x;
  const int row0 = blockIdx.x * ROWS;
  const int col0 = blockIdx.y * CTILE;

  for (int i = tid; i < K * CTILE / 4; i += 256) {
    int k = i / (CTILE / 4);
    int c4 = (i % (CTILE / 4)) * 4;
    *(float4*)&Ws[k][c4] = *(const float4*)&W[(size_t)k * CTOT + col0 + c4];
  }
  for (int i = tid; i < ROWS * K / 4; i += 256) {
    int r = i / (K / 4);
    int k4 = (i % (K / 4)) * 4;
    int gr = row0 + r;
    float4 v = make_float4(0.f, 0.f, 0.f, 0.f);
    if (gr < nrows) v = *(const float4*)&X[(size_t)gr * K + k4];
    *(float4*)&Xs[r][k4] = v;
  }
  __syncthreads();

  const int c0 = (tid & 15) * 4;
  const int r0 = (tid >> 4) * 4;
  float acc[4][4] = {};

#pragma unroll 8
  for (int k = 0; k < K; k++) {
    float4 wv = *(const float4*)&Ws[k][c0];
#pragma unroll
    for (int r = 0; r < 4; r++) {
      float xv = Xs[r0 + r][k];
      acc[r][0] = fmaf(xv, wv.x, acc[r][0]);
      acc[r][1] = fmaf(xv, wv.y, acc[r][1]);
      acc[r][2] = fmaf(xv, wv.z, acc[r][2]);
      acc[r][3] = fmaf(xv, wv.w, acc[r][3]);
    }
  }

#pragma unroll
  for (int r = 0; r < 4; r++) {
    int gr = row0 + r0 + r;
    if (gr < nrows) {
      float s = norm[gr];
      float4 o = make_float4(acc[r][0] * s, acc[r][1] * s, acc[r][2] * s, acc[r][3] * s);
      *(float4*)&Y[(size_t)gr * CTOT + col0 + c0] = o;
    }
  }
}

// ---------------- SpMM: Y[n,:] = relu?( (sum_{e: dst=n} H[src[e],:]) * norm_dst[n] + b ) ----

template <int F, bool RELU>
__global__ __launch_bounds__(256) void spmm_kernel(const float* __restrict__ H,
                                                   const int* __restrict__ offs,
                                                   const int* __restrict__ deg,
                                                   const int* __restrict__ csr,
                                                   const float* __restrict__ norm_dst,
                                                   const float* __restrict__ bias,
                                                   float* __restrict__ Y, int n) {
  constexpr int TPN = F / 4;        // threads per node (float4 lanes)
  constexpr int NPB = 256 / TPN;    // nodes per block
  int node = blockIdx.x * NPB + threadIdx.x / TPN;
  if (node >= n) return;
  int f4 = (threadIdx.x % TPN) * 4;
  int beg = offs[node];
  int end = beg + deg[node];
  float4 acc = make_float4(0.f, 0.f, 0.f, 0.f);
  for (int e = beg; e < end; e++) {
    int s = csr[e];
    const float4 h = *(const float4*)&H[(size_t)s * F + f4];
    acc.x += h.x; acc.y += h.y; acc.z += h.z; acc.w += h.w;
  }
  float nd = norm_dst[node];
  float4 bv = *(const float4*)&bias[f4];
  float4 o = make_float4(fmaf(acc.x, nd, bv.x), fmaf(acc.y, nd, bv.y),
                         fmaf(acc.z, nd, bv.z), fmaf(acc.w, nd, bv.w));
  if (RELU) {
    o.x = fmaxf(o.x, 0.f); o.y = fmaxf(o.y, 0.f);
    o.z = fmaxf(o.z, 0.f); o.w = fmaxf(o.w, 0.f);
  }
  *(float4*)&Y[(size_t)node * F + f4] = o;
}

// ---------------- driver ----------------

extern "C" void kernel_launch(void* const* d_in, const int* in_sizes, int n_in,
                              void* d_out, int out_size, void* d_ws, size_t ws_size,
                              hipStream_t stream) {
  const int N = NNODES;
  const int E = NEDGES;
  const float* W1 = (const float*)d_in[9];
  const float* b1 = (const float*)d_in[10];
  const float* W2 = (const float*)d_in[11];
  const float* b2 = (const float*)d_in[12];

  char* ws = (char*)d_ws;
  size_t off = 0;
  auto alloc = [&](size_t bytes) -> void* {
    void* p = ws + off;
    off += (bytes + 255) & ~(size_t)255;
    return p;
  };
  int* deg_dst = (int*)alloc((size_t)N * 4);
  float* norm_src = (float*)alloc((size_t)N * 4);
  float* norm_dst = (float*)alloc((size_t)N * 4);
  int* offs = (int*)alloc((size_t)N * 4);
  int* bsums = (int*)alloc(512 * 4);
  int* csr = (int*)alloc((size_t)E * 4);
  float* H = (float*)alloc((size_t)N * FHID * 4);  // gemm output; also aliases `part`
  float* T = (float*)alloc((size_t)N * FHID * 4);  // layer-1 output

  // part (2 * NSL * NPAD ints = 12.8 MB) aliases H (51.2 MB): part is dead before
  // the first gemm writes H (stage 4 is the last consumer).
  int* part = (int*)H;
  int* part1 = part + (size_t)NSL * NPAD;  // dst half

  const int nb = (N + 255) / 256;       // 391
  const int gemm_rb = (N + 63) / 64;    // 1563

  for (int g = 0; g < 3; g++) {
    const float* feat = (const float*)d_in[3 * g + 0];
    const int* src = (const int*)d_in[3 * g + 1];
    const int* dst = (const int*)d_in[3 * g + 2];
    float* zout = (float*)d_out + (size_t)g * N * FOUT;

    // ---- CSR build, zero global atomics ----
    hist_part_kernel<<<dim3(NSL, RNG, 2), 256, 0, stream>>>(src, dst, part, E);
    reduce_norm_kernel<<<nb, 256, 0, stream>>>(part, deg_dst, norm_src, norm_dst, N);
    scan_block_kernel<<<nb, 256, 0, stream>>>(deg_dst, offs, bsums, N);
    scan_sums_kernel<<<1, 64, 0, stream>>>(bsums, nb);
    scan_add_kernel<<<nb, 256, 0, stream>>>(offs, bsums, N);
    colscan_kernel<<<nb, 256, 0, stream>>>(part1, offs, N);
    place_kernel<<<dim3(NSL, RNG), 256, 0, stream>>>(src, dst, part1, csr, E);

    // ---- layer 1: H = (feat @ W1) * norm_src ; T = relu(spmm(H) * norm_dst + b1) ----
    gemm_scale<FHID><<<dim3(gemm_rb, FHID / 64), 256, 0, stream>>>(feat, W1, norm_src, H, N);
    {
      constexpr int NPB = 256 / (FHID / 4);  // 8 nodes/block
      spmm_kernel<FHID, true><<<(N + NPB - 1) / NPB, 256, 0, stream>>>(
          H, offs, deg_dst, csr, norm_dst, b1, T, N);
    }

    // ---- layer 2: H = (T @ W2) * norm_src ; z = spmm(H) * norm_dst + b2 ----
    gemm_scale<FOUT><<<dim3(gemm_rb, FOUT / 64), 256, 0, stream>>>(T, W2, norm_src, H, N);
    {
      constexpr int NPB = 256 / (FOUT / 4);  // 16 nodes/block
      spmm_kernel<FOUT, false><<<(N + NPB - 1) / NPB, 256, 0, stream>>>(
          H, offs, deg_dst, csr, norm_dst, b2, zout, N);
    }
  }
}

// Round 3
// 1592.927 us; speedup vs baseline: 1.4838x; 1.4838x over previous
//
#include <hip/hip_runtime.h>

#define NNODES 100000
#define NEDGES 1600000
#define FIN 128
#define FHID 128
#define FOUT 64

// CSR-build geometry: zero global atomics, full occupancy.
// RS*RNG >= N; RS ints = 25 KB LDS -> 6 blocks/CU. NSL slices of the edge list.
#define RNG 16
#define RS 6256
#define NPAD (RNG * RS)          // 100096
#define NSL 64
#define SLICE ((NEDGES + NSL - 1) / NSL)   // 25000

// ---------------- stage 1: per-(slice,range) histograms via LDS ----------------
// grid = (NSL, RNG, 2); z=0 -> src array, z=1 -> dst array.
// part layout: part[a][s][node] at ((a*NSL + s)*NPAD + node). Plain stores only.
__global__ __launch_bounds__(256) void hist_part_kernel(const int* __restrict__ src,
                                                        const int* __restrict__ dst,
                                                        int* __restrict__ part, int E) {
  __shared__ int h[RS];
  const int s = blockIdx.x, r = blockIdx.y, a = blockIdx.z;
  const int lo = r * RS;
  const int* __restrict__ arr = a ? dst : src;
  for (int i = threadIdx.x; i < RS; i += 256) h[i] = 0;
  __syncthreads();
  const int e0 = s * SLICE, e1 = min(e0 + SLICE, E);
  for (int e = e0 + threadIdx.x; e < e1; e += 256) {
    unsigned v = (unsigned)(arr[e] - lo);
    if (v < RS) atomicAdd(&h[v], 1);   // LDS atomic
  }
  __syncthreads();
  int* __restrict__ out = part + ((size_t)a * NSL + s) * NPAD + lo;
  for (int i = threadIdx.x; i < RS; i += 256) out[i] = h[i];
}

// ---------------- stage 2: reduce over slices + fused norms ----------------
__global__ __launch_bounds__(256) void reduce_norm_kernel(const int* __restrict__ part,
                                                          int* __restrict__ deg_dst,
                                                          float* __restrict__ norm_src,
                                                          float* __restrict__ norm_dst, int n) {
  int i = blockIdx.x * 256 + threadIdx.x;
  if (i >= n) return;
  int ds = 0, dd = 0;
#pragma unroll
  for (int s = 0; s < NSL; s++) {
    ds += part[(size_t)s * NPAD + i];
    dd += part[((size_t)NSL + s) * NPAD + i];
  }
  deg_dst[i] = dd;
  norm_src[i] = rsqrtf(fmaxf((float)ds, 1.0f));
  norm_dst[i] = rsqrtf(fmaxf((float)dd, 1.0f));
}

// ---------------- exclusive scan of deg_dst -> offs ----------------
__global__ __launch_bounds__(256) void scan_block_kernel(const int* __restrict__ deg,
                                                         int* __restrict__ offs,
                                                         int* __restrict__ bsums, int n) {
  __shared__ int sh[256];
  int i = blockIdx.x * 256 + threadIdx.x;
  int v = (i < n) ? deg[i] : 0;
  sh[threadIdx.x] = v;
  __syncthreads();
  for (int d = 1; d < 256; d <<= 1) {
    int t = (threadIdx.x >= d) ? sh[threadIdx.x - d] : 0;
    __syncthreads();
    sh[threadIdx.x] += t;
    __syncthreads();
  }
  if (i < n) offs[i] = sh[threadIdx.x] - v;  // exclusive
  if (threadIdx.x == 255) bsums[blockIdx.x] = sh[255];
}

// parallel exclusive scan of the block sums (nb <= 512), one block
__global__ __launch_bounds__(512) void scan_sums_kernel(int* bsums, int nb) {
  __shared__ int sh[512];
  int v = (threadIdx.x < nb) ? bsums[threadIdx.x] : 0;
  sh[threadIdx.x] = v;
  __syncthreads();
  for (int d = 1; d < 512; d <<= 1) {
    int t = (threadIdx.x >= d) ? sh[threadIdx.x - d] : 0;
    __syncthreads();
    sh[threadIdx.x] += t;
    __syncthreads();
  }
  if (threadIdx.x < nb) bsums[threadIdx.x] = sh[threadIdx.x] - v;  // exclusive
}

__global__ __launch_bounds__(256) void scan_add_kernel(int* __restrict__ offs,
                                                       const int* __restrict__ bsums, int n) {
  int i = blockIdx.x * 256 + threadIdx.x;
  if (i < n) offs[i] += bsums[blockIdx.x];
}

// ---------------- stage 3: column scan of dst-counts -> per-slice bases (in place) ----
__global__ __launch_bounds__(256) void colscan_kernel(int* __restrict__ part1,
                                                      const int* __restrict__ offs, int n) {
  int i = blockIdx.x * 256 + threadIdx.x;
  if (i >= n) return;
  int run = offs[i];
#pragma unroll
  for (int s = 0; s < NSL; s++) {
    size_t idx = (size_t)s * NPAD + i;
    int t = part1[idx];
    part1[idx] = run;
    run += t;
  }
}

// ---------------- stage 4: placement; block (slice,range) owns its positions ----------
__global__ __launch_bounds__(256) void place_kernel(const int* __restrict__ src,
                                                    const int* __restrict__ dst,
                                                    const int* __restrict__ part1,
                                                    int* __restrict__ csr, int E) {
  __shared__ int cur[RS];
  const int s = blockIdx.x, r = blockIdx.y;
  const int lo = r * RS;
  const int* __restrict__ base = part1 + (size_t)s * NPAD + lo;
  for (int i = threadIdx.x; i < RS; i += 256) cur[i] = base[i];
  __syncthreads();
  const int e0 = s * SLICE, e1 = min(e0 + SLICE, E);
  for (int e = e0 + threadIdx.x; e < e1; e += 256) {
    int d = dst[e];
    unsigned v = (unsigned)(d - lo);
    if (v < RS) {
      int p = atomicAdd(&cur[v], 1);   // LDS atomic; positions exclusive to this block
      csr[p] = src[e];
    }
  }
}

// ---------------- GEMM: Y[n,c] = norm[n] * sum_k X[n,k] * W[k,c] ----------------

template <int CTOT>
__global__ __launch_bounds__(256) void gemm_scale(const float* __restrict__ X,
                                                  const float* __restrict__ W,
                                                  const float* __restrict__ norm,
                                                  float* __restrict__ Y, int nrows) {
  constexpr int K = 128;
  constexpr int ROWS = 64;
  constexpr int CTILE = 64;
  __shared__ float Xs[ROWS][K];    // 32 KB
  __shared__ float Ws[K][CTILE];   // 32 KB
  const int tid = threadIdx.x;
  const int row0 = blockIdx.x * ROWS;
  const int col0 = blockIdx.y * CTILE;

  for (int i = tid; i < K * CTILE / 4; i += 256) {
    int k = i / (CTILE / 4);
    int c4 = (i % (CTILE / 4)) * 4;
    *(float4*)&Ws[k][c4] = *(const float4*)&W[(size_t)k * CTOT + col0 + c4];
  }
  for (int i = tid; i < ROWS * K / 4; i += 256) {
    int r = i / (K / 4);
    int k4 = (i % (K / 4)) * 4;
    int gr = row0 + r;
    float4 v = make_float4(0.f, 0.f, 0.f, 0.f);
    if (gr < nrows) v = *(const float4*)&X[(size_t)gr * K + k4];
    *(float4*)&Xs[r][k4] = v;
  }
  __syncthreads();

  const int c0 = (tid & 15) * 4;
  const int r0 = (tid >> 4) * 4;
  float acc[4][4] = {};

#pragma unroll 8
  for (int k = 0; k < K; k++) {
    float4 wv = *(const float4*)&Ws[k][c0];
#pragma unroll
    for (int r = 0; r < 4; r++) {
      float xv = Xs[r0 + r][k];
      acc[r][0] = fmaf(xv, wv.x, acc[r][0]);
      acc[r][1] = fmaf(xv, wv.y, acc[r][1]);
      acc[r][2] = fmaf(xv, wv.z, acc[r][2]);
      acc[r][3] = fmaf(xv, wv.w, acc[r][3]);
    }
  }

#pragma unroll
  for (int r = 0; r < 4; r++) {
    int gr = row0 + r0 + r;
    if (gr < nrows) {
      float s = norm[gr];
      float4 o = make_float4(acc[r][0] * s, acc[r][1] * s, acc[r][2] * s, acc[r][3] * s);
      *(float4*)&Y[(size_t)gr * CTOT + col0 + c0] = o;
    }
  }
}

// ---------------- SpMM: Y[n,:] = relu?( (sum_{e: dst=n} H[src[e],:]) * norm_dst[n] + b ) ----

template <int F, bool RELU>
__global__ __launch_bounds__(256) void spmm_kernel(const float* __restrict__ H,
                                                   const int* __restrict__ offs,
                                                   const int* __restrict__ deg,
                                                   const int* __restrict__ csr,
                                                   const float* __restrict__ norm_dst,
                                                   const float* __restrict__ bias,
                                                   float* __restrict__ Y, int n) {
  constexpr int TPN = F / 4;        // threads per node (float4 lanes)
  constexpr int NPB = 256 / TPN;    // nodes per block
  int node = blockIdx.x * NPB + threadIdx.x / TPN;
  if (node >= n) return;
  int f4 = (threadIdx.x % TPN) * 4;
  int beg = offs[node];
  int end = beg + deg[node];
  float4 acc = make_float4(0.f, 0.f, 0.f, 0.f);
  for (int e = beg; e < end; e++) {
    int s = csr[e];
    const float4 h = *(const float4*)&H[(size_t)s * F + f4];
    acc.x += h.x; acc.y += h.y; acc.z += h.z; acc.w += h.w;
  }
  float nd = norm_dst[node];
  float4 bv = *(const float4*)&bias[f4];
  float4 o = make_float4(fmaf(acc.x, nd, bv.x), fmaf(acc.y, nd, bv.y),
                         fmaf(acc.z, nd, bv.z), fmaf(acc.w, nd, bv.w));
  if (RELU) {
    o.x = fmaxf(o.x, 0.f); o.y = fmaxf(o.y, 0.f);
    o.z = fmaxf(o.z, 0.f); o.w = fmaxf(o.w, 0.f);
  }
  *(float4*)&Y[(size_t)node * F + f4] = o;
}

// ---------------- driver ----------------

extern "C" void kernel_launch(void* const* d_in, const int* in_sizes, int n_in,
                              void* d_out, int out_size, void* d_ws, size_t ws_size,
                              hipStream_t stream) {
  const int N = NNODES;
  const int E = NEDGES;
  const float* W1 = (const float*)d_in[9];
  const float* b1 = (const float*)d_in[10];
  const float* W2 = (const float*)d_in[11];
  const float* b2 = (const float*)d_in[12];

  char* ws = (char*)d_ws;
  size_t off = 0;
  auto alloc = [&](size_t bytes) -> void* {
    void* p = ws + off;
    off += (bytes + 255) & ~(size_t)255;
    return p;
  };
  int* deg_dst = (int*)alloc((size_t)N * 4);
  float* norm_src = (float*)alloc((size_t)N * 4);
  float* norm_dst = (float*)alloc((size_t)N * 4);
  int* offs = (int*)alloc((size_t)N * 4);
  int* bsums = (int*)alloc(512 * 4);
  int* csr = (int*)alloc((size_t)E * 4);
  float* H = (float*)alloc((size_t)N * FHID * 4);  // gemm output; also aliases `part`
  float* T = (float*)alloc((size_t)N * FHID * 4);  // layer-1 output

  // part = 2 * NSL * NPAD ints = 51.2 MB, aliased over H (51.2 MB): part is fully
  // consumed (reduce_norm / colscan / place) before the first gemm writes H.
  int* part = (int*)H;
  int* part1 = part + (size_t)NSL * NPAD;  // dst half

  const int nb = (N + 255) / 256;       // 391
  const int gemm_rb = (N + 63) / 64;    // 1563

  for (int g = 0; g < 3; g++) {
    const float* feat = (const float*)d_in[3 * g + 0];
    const int* src = (const int*)d_in[3 * g + 1];
    const int* dst = (const int*)d_in[3 * g + 2];
    float* zout = (float*)d_out + (size_t)g * N * FOUT;

    // ---- CSR build, zero global atomics, all blocks co-resident ----
    hist_part_kernel<<<dim3(NSL, RNG, 2), 256, 0, stream>>>(src, dst, part, E);
    reduce_norm_kernel<<<nb, 256, 0, stream>>>(part, deg_dst, norm_src, norm_dst, N);
    scan_block_kernel<<<nb, 256, 0, stream>>>(deg_dst, offs, bsums, N);
    scan_sums_kernel<<<1, 512, 0, stream>>>(bsums, nb);
    scan_add_kernel<<<nb, 256, 0, stream>>>(offs, bsums, N);
    colscan_kernel<<<nb, 256, 0, stream>>>(part1, offs, N);
    place_kernel<<<dim3(NSL, RNG), 256, 0, stream>>>(src, dst, part1, csr, E);

    // ---- layer 1: H = (feat @ W1) * norm_src ; T = relu(spmm(H) * norm_dst + b1) ----
    gemm_scale<FHID><<<dim3(gemm_rb, FHID / 64), 256, 0, stream>>>(feat, W1, norm_src, H, N);
    {
      constexpr int NPB = 256 / (FHID / 4);  // 8 nodes/block
      spmm_kernel<FHID, true><<<(N + NPB - 1) / NPB, 256, 0, stream>>>(
          H, offs, deg_dst, csr, norm_dst, b1, T, N);
    }

    // ---- layer 2: H = (T @ W2) * norm_src ; z = spmm(H) * norm_dst + b2 ----
    gemm_scale<FOUT><<<dim3(gemm_rb, FOUT / 64), 256, 0, stream>>>(T, W2, norm_src, H, N);
    {
      constexpr int NPB = 256 / (FOUT / 4);  // 16 nodes/block
      spmm_kernel<FOUT, false><<<(N + NPB - 1) / NPB, 256, 0, stream>>>(
          H, offs, deg_dst, csr, norm_dst, b2, zout, N);
    }
  }
}

// Round 4
// 1344.625 us; speedup vs baseline: 1.7578x; 1.1847x over previous
//
#include <hip/hip_runtime.h>

#define NNODES 100000
#define NEDGES 1600000
#define FIN 128
#define FHID 128
#define FOUT 64

typedef unsigned short u16;
typedef unsigned int u32;

// CSR-build geometry: zero global atomics, full occupancy.
// RS ints = 25 KB LDS -> 6 blocks/CU. NSL slices of the edge list.
#define RNG 16
#define RS 6256
#define NPAD (RNG * RS)          // 100096
#define NSL 64
#define SLICE ((NEDGES + NSL - 1) / NSL)   // 25000

__device__ __forceinline__ u16 f2bf(float f) {
  u32 u = __float_as_uint(f);
  u32 r = (u + 0x7fffu + ((u >> 16) & 1u)) >> 16;   // RNE
  return (u16)r;
}

// ---------------- stage 1: per-(slice,range) histograms via LDS ----------------
// grid = (NSL, RNG, 2); z=0 -> src array, z=1 -> dst array.
// part layout (u16): part[a][s][node] at ((a*NSL + s)*NPAD + node). Plain stores only.
__global__ __launch_bounds__(256) void hist_part_kernel(const int* __restrict__ src,
                                                        const int* __restrict__ dst,
                                                        u16* __restrict__ part, int E) {
  __shared__ int h[RS];
  const int s = blockIdx.x, r = blockIdx.y, a = blockIdx.z;
  const int lo = r * RS;
  const int* __restrict__ arr = a ? dst : src;
  for (int i = threadIdx.x; i < RS; i += 256) h[i] = 0;
  __syncthreads();
  const int e0 = s * SLICE, e1 = min(e0 + SLICE, E);
  for (int e = e0 + threadIdx.x; e < e1; e += 256) {
    unsigned v = (unsigned)(arr[e] - lo);
    if (v < RS) atomicAdd(&h[v], 1);   // LDS atomic
  }
  __syncthreads();
  u16* __restrict__ out = part + ((size_t)a * NSL + s) * NPAD + lo;
  for (int i = threadIdx.x; i < RS; i += 256) out[i] = (u16)h[i];  // count <= 25000
}

// ---------------- stage 2: reduce over slices + fused norms ----------------
__global__ __launch_bounds__(256) void reduce_norm_kernel(const u16* __restrict__ part,
                                                          int* __restrict__ deg_dst,
                                                          float* __restrict__ norm_src,
                                                          float* __restrict__ norm_dst, int n) {
  int i = blockIdx.x * 256 + threadIdx.x;
  if (i >= n) return;
  int ds = 0, dd = 0;
#pragma unroll
  for (int s = 0; s < NSL; s++) {
    ds += part[(size_t)s * NPAD + i];
    dd += part[((size_t)NSL + s) * NPAD + i];
  }
  deg_dst[i] = dd;
  norm_src[i] = rsqrtf(fmaxf((float)ds, 1.0f));
  norm_dst[i] = rsqrtf(fmaxf((float)dd, 1.0f));
}

// ---------------- exclusive scan of deg_dst -> offs ----------------
__global__ __launch_bounds__(256) void scan_block_kernel(const int* __restrict__ deg,
                                                         int* __restrict__ offs,
                                                         int* __restrict__ bsums, int n) {
  __shared__ int sh[256];
  int i = blockIdx.x * 256 + threadIdx.x;
  int v = (i < n) ? deg[i] : 0;
  sh[threadIdx.x] = v;
  __syncthreads();
  for (int d = 1; d < 256; d <<= 1) {
    int t = (threadIdx.x >= d) ? sh[threadIdx.x - d] : 0;
    __syncthreads();
    sh[threadIdx.x] += t;
    __syncthreads();
  }
  if (i < n) offs[i] = sh[threadIdx.x] - v;  // exclusive
  if (threadIdx.x == 255) bsums[blockIdx.x] = sh[255];
}

__global__ __launch_bounds__(512) void scan_sums_kernel(int* bsums, int nb) {
  __shared__ int sh[512];
  int v = (threadIdx.x < nb) ? bsums[threadIdx.x] : 0;
  sh[threadIdx.x] = v;
  __syncthreads();
  for (int d = 1; d < 512; d <<= 1) {
    int t = (threadIdx.x >= d) ? sh[threadIdx.x - d] : 0;
    __syncthreads();
    sh[threadIdx.x] += t;
    __syncthreads();
  }
  if (threadIdx.x < nb) bsums[threadIdx.x] = sh[threadIdx.x] - v;  // exclusive
}

__global__ __launch_bounds__(256) void scan_add_kernel(int* __restrict__ offs,
                                                       const int* __restrict__ bsums, int n) {
  int i = blockIdx.x * 256 + threadIdx.x;
  if (i < n) offs[i] += bsums[blockIdx.x];
}

// ---------------- stage 3: column scan of dst-counts -> per-slice bases ----------------
__global__ __launch_bounds__(256) void colscan_kernel(const u16* __restrict__ part1,
                                                      u32* __restrict__ base,
                                                      const int* __restrict__ offs, int n) {
  int i = blockIdx.x * 256 + threadIdx.x;
  if (i >= n) return;
  int run = offs[i];
#pragma unroll
  for (int s = 0; s < NSL; s++) {
    size_t idx = (size_t)s * NPAD + i;
    base[idx] = (u32)run;
    run += part1[idx];
  }
}

// ---------------- stage 4: placement; block (slice,range) owns its positions ----------
__global__ __launch_bounds__(256) void place_kernel(const int* __restrict__ src,
                                                    const int* __restrict__ dst,
                                                    const u32* __restrict__ base,
                                                    int* __restrict__ csr, int E) {
  __shared__ int cur[RS];
  const int s = blockIdx.x, r = blockIdx.y;
  const int lo = r * RS;
  const u32* __restrict__ b = base + (size_t)s * NPAD + lo;
  for (int i = threadIdx.x; i < RS; i += 256) cur[i] = (int)b[i];
  __syncthreads();
  const int e0 = s * SLICE, e1 = min(e0 + SLICE, E);
  for (int e = e0 + threadIdx.x; e < e1; e += 256) {
    int d = dst[e];
    unsigned v = (unsigned)(d - lo);
    if (v < RS) {
      int p = atomicAdd(&cur[v], 1);   // LDS atomic; positions exclusive to this block
      csr[p] = src[e];
    }
  }
}

// ---- GEMM: Yb[n,c] = bf16( norm[n] * sum_k X[n,k] * W[k,c] ), fp32 compute ----

template <int CTOT>
__global__ __launch_bounds__(256) void gemm_scale_bf16(const float* __restrict__ X,
                                                       const float* __restrict__ W,
                                                       const float* __restrict__ norm,
                                                       u16* __restrict__ Y, int nrows) {
  constexpr int K = 128;
  constexpr int ROWS = 64;
  constexpr int CTILE = 64;
  __shared__ float Xs[ROWS][K];    // 32 KB
  __shared__ float Ws[K][CTILE];   // 32 KB
  const int tid = threadIdx.x;
  const int row0 = blockIdx.x * ROWS;
  const int col0 = blockIdx.y * CTILE;

  for (int i = tid; i < K * CTILE / 4; i += 256) {
    int k = i / (CTILE / 4);
    int c4 = (i % (CTILE / 4)) * 4;
    *(float4*)&Ws[k][c4] = *(const float4*)&W[(size_t)k * CTOT + col0 + c4];
  }
  for (int i = tid; i < ROWS * K / 4; i += 256) {
    int r = i / (K / 4);
    int k4 = (i % (K / 4)) * 4;
    int gr = row0 + r;
    float4 v = make_float4(0.f, 0.f, 0.f, 0.f);
    if (gr < nrows) v = *(const float4*)&X[(size_t)gr * K + k4];
    *(float4*)&Xs[r][k4] = v;
  }
  __syncthreads();

  const int c0 = (tid & 15) * 4;
  const int r0 = (tid >> 4) * 4;
  float acc[4][4] = {};

#pragma unroll 8
  for (int k = 0; k < K; k++) {
    float4 wv = *(const float4*)&Ws[k][c0];
#pragma unroll
    for (int r = 0; r < 4; r++) {
      float xv = Xs[r0 + r][k];
      acc[r][0] = fmaf(xv, wv.x, acc[r][0]);
      acc[r][1] = fmaf(xv, wv.y, acc[r][1]);
      acc[r][2] = fmaf(xv, wv.z, acc[r][2]);
      acc[r][3] = fmaf(xv, wv.w, acc[r][3]);
    }
  }

#pragma unroll
  for (int r = 0; r < 4; r++) {
    int gr = row0 + r0 + r;
    if (gr < nrows) {
      float s = norm[gr];
      ushort4 o;
      o.x = f2bf(acc[r][0] * s);
      o.y = f2bf(acc[r][1] * s);
      o.z = f2bf(acc[r][2] * s);
      o.w = f2bf(acc[r][3] * s);
      *(ushort4*)&Y[(size_t)gr * CTOT + col0 + c0] = o;
    }
  }
}

// ---- SpMM: Y[n,:] = relu?( (sum_{e: dst=n} Hb[src[e],:]) * norm_dst[n] + b ), bf16 gather ----

template <int F, bool RELU>
__global__ __launch_bounds__(256) void spmm_bf16(const u16* __restrict__ Hb,
                                                 const int* __restrict__ offs,
                                                 const int* __restrict__ deg,
                                                 const int* __restrict__ csr,
                                                 const float* __restrict__ norm_dst,
                                                 const float* __restrict__ bias,
                                                 float* __restrict__ Y, int n) {
  constexpr int TPN = F / 8;        // threads per node (8 bf16 = 16 B per lane)
  constexpr int NPB = 256 / TPN;    // nodes per block
  int node = blockIdx.x * NPB + threadIdx.x / TPN;
  if (node >= n) return;
  int f0 = (threadIdx.x % TPN) * 8;
  int beg = offs[node];
  int end = beg + deg[node];
  float acc[8] = {};
  for (int e = beg; e < end; e++) {
    int s = csr[e];
    uint4 p = *(const uint4*)&Hb[(size_t)s * F + f0];
    acc[0] += __uint_as_float(p.x << 16);
    acc[1] += __uint_as_float(p.x & 0xffff0000u);
    acc[2] += __uint_as_float(p.y << 16);
    acc[3] += __uint_as_float(p.y & 0xffff0000u);
    acc[4] += __uint_as_float(p.z << 16);
    acc[5] += __uint_as_float(p.z & 0xffff0000u);
    acc[6] += __uint_as_float(p.w << 16);
    acc[7] += __uint_as_float(p.w & 0xffff0000u);
  }
  float nd = norm_dst[node];
  const float4 b0 = *(const float4*)&bias[f0];
  const float4 b1 = *(const float4*)&bias[f0 + 4];
  float4 o0, o1;
  o0.x = fmaf(acc[0], nd, b0.x); o0.y = fmaf(acc[1], nd, b0.y);
  o0.z = fmaf(acc[2], nd, b0.z); o0.w = fmaf(acc[3], nd, b0.w);
  o1.x = fmaf(acc[4], nd, b1.x); o1.y = fmaf(acc[5], nd, b1.y);
  o1.z = fmaf(acc[6], nd, b1.z); o1.w = fmaf(acc[7], nd, b1.w);
  if (RELU) {
    o0.x = fmaxf(o0.x, 0.f); o0.y = fmaxf(o0.y, 0.f);
    o0.z = fmaxf(o0.z, 0.f); o0.w = fmaxf(o0.w, 0.f);
    o1.x = fmaxf(o1.x, 0.f); o1.y = fmaxf(o1.y, 0.f);
    o1.z = fmaxf(o1.z, 0.f); o1.w = fmaxf(o1.w, 0.f);
  }
  *(float4*)&Y[(size_t)node * F + f0] = o0;
  *(float4*)&Y[(size_t)node * F + f0 + 4] = o1;
}

// ---------------- driver ----------------

extern "C" void kernel_launch(void* const* d_in, const int* in_sizes, int n_in,
                              void* d_out, int out_size, void* d_ws, size_t ws_size,
                              hipStream_t stream) {
  const int N = NNODES;
  const int E = NEDGES;
  const float* W1 = (const float*)d_in[9];
  const float* b1 = (const float*)d_in[10];
  const float* W2 = (const float*)d_in[11];
  const float* b2 = (const float*)d_in[12];

  char* ws = (char*)d_ws;
  size_t off = 0;
  auto alloc = [&](size_t bytes) -> void* {
    void* p = ws + off;
    off += (bytes + 255) & ~(size_t)255;
    return p;
  };
  int* deg_dst = (int*)alloc((size_t)N * 4);
  float* norm_src = (float*)alloc((size_t)N * 4);
  float* norm_dst = (float*)alloc((size_t)N * 4);
  int* offs = (int*)alloc((size_t)N * 4);
  int* bsums = (int*)alloc(512 * 4);
  int* csr = (int*)alloc((size_t)E * 4);
  u16* H = (u16*)alloc((size_t)N * FHID * 2);      // bf16 gemm output; aliases `part`
  float* T = (float*)alloc((size_t)N * FHID * 4);  // fp32 layer-1 output; aliases `base`

  // part (u16, 2*NSL*NPAD = 25.6 MB) aliases H (25.6 MB): part is dead before gemm1
  // writes H. base (u32, NSL*NPAD = 25.6 MB) aliases T (51.2 MB): base is dead after
  // place_kernel, before spmm1 writes T.
  u16* part = (u16*)H;
  u16* part1 = part + (size_t)NSL * NPAD;  // dst half
  u32* base = (u32*)T;

  const int nb = (N + 255) / 256;       // 391
  const int gemm_rb = (N + 63) / 64;    // 1563

  for (int g = 0; g < 3; g++) {
    const float* feat = (const float*)d_in[3 * g + 0];
    const int* src = (const int*)d_in[3 * g + 1];
    const int* dst = (const int*)d_in[3 * g + 2];
    float* zout = (float*)d_out + (size_t)g * N * FOUT;

    // ---- CSR build, zero global atomics, all blocks co-resident ----
    hist_part_kernel<<<dim3(NSL, RNG, 2), 256, 0, stream>>>(src, dst, part, E);
    reduce_norm_kernel<<<nb, 256, 0, stream>>>(part, deg_dst, norm_src, norm_dst, N);
    scan_block_kernel<<<nb, 256, 0, stream>>>(deg_dst, offs, bsums, N);
    scan_sums_kernel<<<1, 512, 0, stream>>>(bsums, nb);
    scan_add_kernel<<<nb, 256, 0, stream>>>(offs, bsums, N);
    colscan_kernel<<<nb, 256, 0, stream>>>(part1, base, offs, N);
    place_kernel<<<dim3(NSL, RNG), 256, 0, stream>>>(src, dst, base, csr, E);

    // ---- layer 1: H = bf16((feat @ W1) * norm_src) ; T = relu(spmm(H)*norm_dst + b1) ----
    gemm_scale_bf16<FHID><<<dim3(gemm_rb, FHID / 64), 256, 0, stream>>>(feat, W1, norm_src, H, N);
    {
      constexpr int NPB = 256 / (FHID / 8);  // 16 nodes/block
      spmm_bf16<FHID, true><<<(N + NPB - 1) / NPB, 256, 0, stream>>>(
          H, offs, deg_dst, csr, norm_dst, b1, T, N);
    }

    // ---- layer 2: H = bf16((T @ W2) * norm_src) ; z = spmm(H)*norm_dst + b2 ----
    gemm_scale_bf16<FOUT><<<dim3(gemm_rb, FOUT / 64), 256, 0, stream>>>(T, W2, norm_src, H, N);
    {
      constexpr int NPB = 256 / (FOUT / 8);  // 32 nodes/block
      spmm_bf16<FOUT, false><<<(N + NPB - 1) / NPB, 256, 0, stream>>>(
          H, offs, deg_dst, csr, norm_dst, b2, zout, N);
    }
  }
}

// Round 5
// 1182.617 us; speedup vs baseline: 1.9986x; 1.1370x over previous
//
#include <hip/hip_runtime.h>

#define NNODES 100000
#define NEDGES 1600000
#define FIN 128
#define FHID 128
#define FOUT 64

typedef unsigned short u16;
typedef unsigned int u32;
typedef __attribute__((ext_vector_type(8))) short short8;
typedef __attribute__((ext_vector_type(4))) float floatx4;

// CSR-build geometry: zero global atomics, full occupancy.
#define RNG 16
#define RS 6256
#define NPAD (RNG * RS)          // 100096
#define NSL 64
#define SLICE ((NEDGES + NSL - 1) / NSL)   // 25000

__device__ __forceinline__ u16 f2bf(float f) {
  u32 u = __float_as_uint(f);
  u32 r = (u + 0x7fffu + ((u >> 16) & 1u)) >> 16;   // RNE
  return (u16)r;
}

// ---------------- stage 1: per-(slice,range) histograms via LDS ----------------
__global__ __launch_bounds__(256) void hist_part_kernel(const int* __restrict__ src,
                                                        const int* __restrict__ dst,
                                                        u16* __restrict__ part, int E) {
  __shared__ int h[RS];
  const int s = blockIdx.x, r = blockIdx.y, a = blockIdx.z;
  const int lo = r * RS;
  const int* __restrict__ arr = a ? dst : src;
  for (int i = threadIdx.x; i < RS; i += 256) h[i] = 0;
  __syncthreads();
  const int e0 = s * SLICE, e1 = min(e0 + SLICE, E);
  for (int e = e0 + threadIdx.x; e < e1; e += 256) {
    unsigned v = (unsigned)(arr[e] - lo);
    if (v < RS) atomicAdd(&h[v], 1);   // LDS atomic
  }
  __syncthreads();
  u16* __restrict__ out = part + ((size_t)a * NSL + s) * NPAD + lo;
  for (int i = threadIdx.x; i < RS; i += 256) out[i] = (u16)h[i];
}

// ---------------- stage 2: reduce over slices + fused norms ----------------
__global__ __launch_bounds__(256) void reduce_norm_kernel(const u16* __restrict__ part,
                                                          int* __restrict__ deg_dst,
                                                          float* __restrict__ norm_src,
                                                          float* __restrict__ norm_dst, int n) {
  int i = blockIdx.x * 256 + threadIdx.x;
  if (i >= n) return;
  int ds = 0, dd = 0;
#pragma unroll
  for (int s = 0; s < NSL; s++) {
    ds += part[(size_t)s * NPAD + i];
    dd += part[((size_t)NSL + s) * NPAD + i];
  }
  deg_dst[i] = dd;
  norm_src[i] = rsqrtf(fmaxf((float)ds, 1.0f));
  norm_dst[i] = rsqrtf(fmaxf((float)dd, 1.0f));
}

// ---------------- exclusive scan of deg_dst -> offs ----------------
__global__ __launch_bounds__(256) void scan_block_kernel(const int* __restrict__ deg,
                                                         int* __restrict__ offs,
                                                         int* __restrict__ bsums, int n) {
  __shared__ int sh[256];
  int i = blockIdx.x * 256 + threadIdx.x;
  int v = (i < n) ? deg[i] : 0;
  sh[threadIdx.x] = v;
  __syncthreads();
  for (int d = 1; d < 256; d <<= 1) {
    int t = (threadIdx.x >= d) ? sh[threadIdx.x - d] : 0;
    __syncthreads();
    sh[threadIdx.x] += t;
    __syncthreads();
  }
  if (i < n) offs[i] = sh[threadIdx.x] - v;  // exclusive
  if (threadIdx.x == 255) bsums[blockIdx.x] = sh[255];
}

__global__ __launch_bounds__(512) void scan_sums_kernel(int* bsums, int nb) {
  __shared__ int sh[512];
  int v = (threadIdx.x < nb) ? bsums[threadIdx.x] : 0;
  sh[threadIdx.x] = v;
  __syncthreads();
  for (int d = 1; d < 512; d <<= 1) {
    int t = (threadIdx.x >= d) ? sh[threadIdx.x - d] : 0;
    __syncthreads();
    sh[threadIdx.x] += t;
    __syncthreads();
  }
  if (threadIdx.x < nb) bsums[threadIdx.x] = sh[threadIdx.x] - v;  // exclusive
}

__global__ __launch_bounds__(256) void scan_add_kernel(int* __restrict__ offs,
                                                       const int* __restrict__ bsums, int n) {
  int i = blockIdx.x * 256 + threadIdx.x;
  if (i < n) offs[i] += bsums[blockIdx.x];
}

// ---------------- stage 3: column scan of dst-counts -> per-slice bases ----------------
__global__ __launch_bounds__(256) void colscan_kernel(const u16* __restrict__ part1,
                                                      u32* __restrict__ base,
                                                      const int* __restrict__ offs, int n) {
  int i = blockIdx.x * 256 + threadIdx.x;
  if (i >= n) return;
  int run = offs[i];
#pragma unroll
  for (int s = 0; s < NSL; s++) {
    size_t idx = (size_t)s * NPAD + i;
    base[idx] = (u32)run;
    run += part1[idx];
  }
}

// ---------------- stage 4: placement; block (slice,range) owns its positions ----------
__global__ __launch_bounds__(256) void place_kernel(const int* __restrict__ src,
                                                    const int* __restrict__ dst,
                                                    const u32* __restrict__ base,
                                                    int* __restrict__ csr, int E) {
  __shared__ int cur[RS];
  const int s = blockIdx.x, r = blockIdx.y;
  const int lo = r * RS;
  const u32* __restrict__ b = base + (size_t)s * NPAD + lo;
  for (int i = threadIdx.x; i < RS; i += 256) cur[i] = (int)b[i];
  __syncthreads();
  const int e0 = s * SLICE, e1 = min(e0 + SLICE, E);
  for (int e = e0 + threadIdx.x; e < e1; e += 256) {
    int d = dst[e];
    unsigned v = (unsigned)(d - lo);
    if (v < RS) {
      int p = atomicAdd(&cur[v], 1);   // LDS atomic; positions exclusive to this block
      csr[p] = src[e];
    }
  }
}

// ---- MFMA GEMM: Yb[n,c] = bf16( norm[n] * sum_k X[n,k] * W[k,c] ) ----
// 64x64 tile, K=128 in LDS (bf16, padded stride 136 -> 4-bank row rotation).
// 4 waves x 16 rows; A-frags in regs; mfma_f32_16x16x32_bf16, fp32 accum.

#define XP 136   // padded LDS row stride in u16

template <int CTOT, bool IN_BF16>
__global__ __launch_bounds__(256) void gemm_mfma(const void* __restrict__ Xv,
                                                 const float* __restrict__ W,
                                                 const float* __restrict__ norm,
                                                 u16* __restrict__ Y, int nrows) {
  __shared__ u16 Xs[64 * XP];   // 17408 B
  __shared__ u16 Wt[64 * XP];   // 17408 B, Wt[n][k] = W[k][col0+n]
  __shared__ float norm_s[64];
  const int tid = threadIdx.x;
  const int row0 = blockIdx.x * 64;
  const int col0 = blockIdx.y * 64;

  // stage X tile (64 rows x 128 k) as bf16
  if constexpr (IN_BF16) {
    const u16* X = (const u16*)Xv;
    for (int i = tid; i < 64 * 16; i += 256) {       // 16 uint4 per row
      int r = i >> 4, k8 = (i & 15) * 8;
      int gr = row0 + r;
      uint4 v = make_uint4(0u, 0u, 0u, 0u);
      if (gr < nrows) v = *(const uint4*)&X[(size_t)gr * 128 + k8];
      *(uint4*)&Xs[r * XP + k8] = v;
    }
  } else {
    const float* X = (const float*)Xv;
    for (int i = tid; i < 64 * 32; i += 256) {       // 32 float4 per row
      int r = i >> 5, k4 = (i & 31) * 4;
      int gr = row0 + r;
      ushort4 o = make_ushort4(0, 0, 0, 0);
      if (gr < nrows) {
        float4 v = *(const float4*)&X[(size_t)gr * 128 + k4];
        o.x = f2bf(v.x); o.y = f2bf(v.y); o.z = f2bf(v.z); o.w = f2bf(v.w);
      }
      *(ushort4*)&Xs[r * XP + k4] = o;
    }
  }
  // stage W tile transposed (64 cols x 128 k) as bf16
  for (int i = tid; i < 128 * 16; i += 256) {        // K x 16 float4-groups
    int k = i >> 4, c4 = (i & 15) * 4;
    float4 v = *(const float4*)&W[(size_t)k * CTOT + col0 + c4];
    Wt[(c4 + 0) * XP + k] = f2bf(v.x);
    Wt[(c4 + 1) * XP + k] = f2bf(v.y);
    Wt[(c4 + 2) * XP + k] = f2bf(v.z);
    Wt[(c4 + 3) * XP + k] = f2bf(v.w);
  }
  if (tid < 64) norm_s[tid] = (row0 + tid < nrows) ? norm[row0 + tid] : 0.f;
  __syncthreads();

  const int w = tid >> 6, lane = tid & 63;
  const int quad = lane >> 4, r16 = lane & 15;
  const int arow = w * 16 + r16;   // A-fragment row within tile

  short8 a[4];
#pragma unroll
  for (int kc = 0; kc < 4; kc++)
    a[kc] = *(const short8*)&Xs[arow * XP + kc * 32 + quad * 8];

#pragma unroll
  for (int nc = 0; nc < 4; nc++) {
    floatx4 acc = {0.f, 0.f, 0.f, 0.f};
#pragma unroll
    for (int kc = 0; kc < 4; kc++) {
      short8 b = *(const short8*)&Wt[(nc * 16 + r16) * XP + kc * 32 + quad * 8];
      acc = __builtin_amdgcn_mfma_f32_16x16x32_bf16(a[kc], b, acc, 0, 0, 0);
    }
#pragma unroll
    for (int i = 0; i < 4; i++) {
      int lr = w * 16 + quad * 4 + i;     // C/D: row = quad*4+reg, col = r16
      int gr = row0 + lr;
      if (gr < nrows)
        Y[(size_t)gr * CTOT + col0 + nc * 16 + r16] = f2bf(acc[i] * norm_s[lr]);
    }
  }
}

// ---- SpMM: Y[n,:] = relu?( (sum_{e: dst=n} Hb[src[e],:]) * norm_dst[n] + b ) ----
// bf16 gather, fp32 accumulate; output bf16 (mid pipeline) or fp32 (final).

template <int F, bool RELU, bool OUT_BF16>
__global__ __launch_bounds__(256) void spmm_bf16(const u16* __restrict__ Hb,
                                                 const int* __restrict__ offs,
                                                 const int* __restrict__ deg,
                                                 const int* __restrict__ csr,
                                                 const float* __restrict__ norm_dst,
                                                 const float* __restrict__ bias,
                                                 void* __restrict__ Yv, int n) {
  constexpr int TPN = F / 8;        // threads per node (8 bf16 = 16 B per lane)
  constexpr int NPB = 256 / TPN;    // nodes per block
  int node = blockIdx.x * NPB + threadIdx.x / TPN;
  if (node >= n) return;
  int f0 = (threadIdx.x % TPN) * 8;
  int beg = offs[node];
  int end = beg + deg[node];
  float acc[8] = {};
  for (int e = beg; e < end; e++) {
    int s = csr[e];
    uint4 p = *(const uint4*)&Hb[(size_t)s * F + f0];
    acc[0] += __uint_as_float(p.x << 16);
    acc[1] += __uint_as_float(p.x & 0xffff0000u);
    acc[2] += __uint_as_float(p.y << 16);
    acc[3] += __uint_as_float(p.y & 0xffff0000u);
    acc[4] += __uint_as_float(p.z << 16);
    acc[5] += __uint_as_float(p.z & 0xffff0000u);
    acc[6] += __uint_as_float(p.w << 16);
    acc[7] += __uint_as_float(p.w & 0xffff0000u);
  }
  float nd = norm_dst[node];
  float o[8];
#pragma unroll
  for (int i = 0; i < 8; i++) {
    o[i] = fmaf(acc[i], nd, bias[f0 + i]);
    if (RELU) o[i] = fmaxf(o[i], 0.f);
  }
  if constexpr (OUT_BF16) {
    u16* Y = (u16*)Yv;
    uint4 pk;
    pk.x = (u32)f2bf(o[0]) | ((u32)f2bf(o[1]) << 16);
    pk.y = (u32)f2bf(o[2]) | ((u32)f2bf(o[3]) << 16);
    pk.z = (u32)f2bf(o[4]) | ((u32)f2bf(o[5]) << 16);
    pk.w = (u32)f2bf(o[6]) | ((u32)f2bf(o[7]) << 16);
    *(uint4*)&Y[(size_t)node * F + f0] = pk;
  } else {
    float* Y = (float*)Yv;
    *(float4*)&Y[(size_t)node * F + f0] = make_float4(o[0], o[1], o[2], o[3]);
    *(float4*)&Y[(size_t)node * F + f0 + 4] = make_float4(o[4], o[5], o[6], o[7]);
  }
}

// ---------------- driver ----------------

extern "C" void kernel_launch(void* const* d_in, const int* in_sizes, int n_in,
                              void* d_out, int out_size, void* d_ws, size_t ws_size,
                              hipStream_t stream) {
  const int N = NNODES;
  const int E = NEDGES;
  const float* W1 = (const float*)d_in[9];
  const float* b1 = (const float*)d_in[10];
  const float* W2 = (const float*)d_in[11];
  const float* b2 = (const float*)d_in[12];

  char* ws = (char*)d_ws;
  size_t off = 0;
  auto alloc = [&](size_t bytes) -> void* {
    void* p = ws + off;
    off += (bytes + 255) & ~(size_t)255;
    return p;
  };
  int* deg_dst = (int*)alloc((size_t)N * 4);
  float* norm_src = (float*)alloc((size_t)N * 4);
  float* norm_dst = (float*)alloc((size_t)N * 4);
  int* offs = (int*)alloc((size_t)N * 4);
  int* bsums = (int*)alloc(512 * 4);
  int* csr = (int*)alloc((size_t)E * 4);
  // H (bf16 gemm output, 25.6 MB) aliases `part` (u16 2*NSL*NPAD = 25.6 MB):
  // part is dead before gemm1 writes H.
  u16* H = (u16*)alloc((size_t)2 * NSL * NPAD * 2);
  // T (bf16 spmm1 output, 25.6 MB) aliases `base` (u32 NSL*NPAD = 25.6 MB):
  // base is dead after place_kernel, before spmm1 writes T.
  u16* T = (u16*)alloc((size_t)NSL * NPAD * 4);

  u16* part = (u16*)H;
  u16* part1 = part + (size_t)NSL * NPAD;  // dst half
  u32* base = (u32*)T;

  const int nb = (N + 255) / 256;       // 391
  const int gemm_rb = (N + 63) / 64;    // 1563

  for (int g = 0; g < 3; g++) {
    const float* feat = (const float*)d_in[3 * g + 0];
    const int* src = (const int*)d_in[3 * g + 1];
    const int* dst = (const int*)d_in[3 * g + 2];
    float* zout = (float*)d_out + (size_t)g * N * FOUT;

    // ---- CSR build, zero global atomics, all blocks co-resident ----
    hist_part_kernel<<<dim3(NSL, RNG, 2), 256, 0, stream>>>(src, dst, part, E);
    reduce_norm_kernel<<<nb, 256, 0, stream>>>(part, deg_dst, norm_src, norm_dst, N);
    scan_block_kernel<<<nb, 256, 0, stream>>>(deg_dst, offs, bsums, N);
    scan_sums_kernel<<<1, 512, 0, stream>>>(bsums, nb);
    scan_add_kernel<<<nb, 256, 0, stream>>>(offs, bsums, N);
    colscan_kernel<<<nb, 256, 0, stream>>>(part1, base, offs, N);
    place_kernel<<<dim3(NSL, RNG), 256, 0, stream>>>(src, dst, base, csr, E);

    // ---- layer 1: H = bf16((feat @ W1) * norm_src) ; T = bf16(relu(spmm(H)*nd + b1)) ----
    gemm_mfma<FHID, false><<<dim3(gemm_rb, FHID / 64), 256, 0, stream>>>(
        feat, W1, norm_src, H, N);
    {
      constexpr int NPB = 256 / (FHID / 8);  // 16 nodes/block
      spmm_bf16<FHID, true, true><<<(N + NPB - 1) / NPB, 256, 0, stream>>>(
          H, offs, deg_dst, csr, norm_dst, b1, T, N);
    }

    // ---- layer 2: H = bf16((T @ W2) * norm_src) ; z = spmm(H)*nd + b2 (fp32) ----
    gemm_mfma<FOUT, true><<<dim3(gemm_rb, FOUT / 64), 256, 0, stream>>>(
        T, W2, norm_src, H, N);
    {
      constexpr int NPB = 256 / (FOUT / 8);  // 32 nodes/block
      spmm_bf16<FOUT, false, false><<<(N + NPB - 1) / NPB, 256, 0, stream>>>(
          H, offs, deg_dst, csr, norm_dst, b2, zout, N);
    }
  }
}